// Round 10
// baseline (204.163 us; speedup 1.0000x reference)
//
#include <hip/hip_runtime.h>

typedef __attribute__((ext_vector_type(8))) short bf16x8;
typedef __attribute__((ext_vector_type(4))) float f32x4;

#define GAMMA_ 0.5f
#define LOG2E_ 1.4426950408889634f

constexpr int D      = 256;   // feature dim (K)
constexpr int BM     = 128;   // rows of X per block (2 row-groups of 64)
constexpr int JSPLIT = 16;    // split of M across blockIdx.y

// LDS layout (bytes):
//   [0, 49152)      : per-wave B rings, wave w at [w*12288, +12K): 3 slots x 4KB
//   [49152, 51200)  : tcol panel (512 x f32)
//   [51200, 53248)  : coef panel (512 x f32)
//   [53248, 53760)  : srow panel (128 x f32)
// total 52.5 KB -> 3 blocks/CU (3 x 53760 = 161280 <= 163840)
constexpr int AUX_TCOL  = 49152;
constexpr int AUX_COEF  = 51200;
constexpr int AUX_SROW  = 53248;
constexpr int LDS_BYTES = 53760;

// ---------- helpers ----------
__device__ __forceinline__ unsigned short f2bf(float f) {
    unsigned int x = __float_as_uint(f);
    x += 0x7FFFu + ((x >> 16) & 1u);          // RNE
    return (unsigned short)(x >> 16);
}

__device__ __forceinline__ void gload16(void* lds, const void* g) {
    __builtin_amdgcn_global_load_lds(
        (const __attribute__((address_space(1))) void*)g,
        (__attribute__((address_space(3))) void*)lds, 16, 0, 0);
}

// ---------- prep: cast to bf16, row |x|^2, coefs, out-init ----------
__global__ void prep_all_kernel(const float* __restrict__ X,
                                const float* __restrict__ Xt,
                                const float* __restrict__ alphas,
                                const float* __restrict__ y,
                                const float* __restrict__ b,
                                unsigned short* __restrict__ Abf,
                                unsigned short* __restrict__ Bbf,
                                float* __restrict__ srow,
                                float* __restrict__ tcol,
                                float* __restrict__ coef,
                                float* __restrict__ out,
                                int N, int M) {
    int w = threadIdx.x >> 6;         // one wave per row
    int l = threadIdx.x & 63;
    int row = blockIdx.x * 4 + w;
    if (row >= N + M) return;
    const float* src;
    unsigned short* dst;
    if (row < N) { src = X  + (size_t)row * D;       dst = Abf + (size_t)row * D; }
    else         { src = Xt + (size_t)(row - N) * D; dst = Bbf + (size_t)(row - N) * D; }
    const float4 v = reinterpret_cast<const float4*>(src)[l];
    ushort4 u;
    u.x = f2bf(v.x); u.y = f2bf(v.y); u.z = f2bf(v.z); u.w = f2bf(v.w);
    reinterpret_cast<ushort4*>(dst)[l] = u;
    float ss = v.x * v.x + v.y * v.y + v.z * v.z + v.w * v.w;
    #pragma unroll
    for (int off = 32; off >= 1; off >>= 1) ss += __shfl_xor(ss, off);
    if (l == 0) {
        float folded = -GAMMA_ * LOG2E_ * ss;
        if (row < N) { srow[row] = folded; out[row] = b[0]; }
        else {
            int r2 = row - N;
            tcol[r2] = folded;
            coef[r2] = alphas[r2] * y[r2];
        }
    }
}

// ---------- fused RBF-SVM predict: barrier-free wave-private pipeline ----------
// pred_i = sum_j exp2( s_i + t_j + (2*g*log2e) * <x_i, xt_j> ) * coef_j + b
// Each wave owns rows [wr*64,+64) x its private col stream (wc half of each
// 64-col tile). B staged into a wave-private 3-slot LDS ring via
// global_load_lds; per-wave counted vmcnt; NO barriers in the main loop.
// LDS trimmed to 52.5 KB -> 3 blocks/CU -> 3 waves/SIMD (TLP is the lever).
__launch_bounds__(256, 3)
__global__ void svm_main_kernel(const unsigned short* __restrict__ Abf,
                                const unsigned short* __restrict__ Bbf,
                                const float* __restrict__ srow,
                                const float* __restrict__ tcol,
                                const float* __restrict__ coef,
                                float* __restrict__ out,
                                int M) {
    __shared__ char L[LDS_BYTES];

    const int tid = threadIdx.x;
    const int w   = tid >> 6;          // wave 0..3
    const int l   = tid & 63;
    const int wr  = w >> 1;            // row group 0..1
    const int wc  = w & 1;             // col half 0..1 (wave-private cols)
    const int hi  = l >> 4;            // 0..3
    const int lo  = l & 15;
    const int row0   = blockIdx.x * BM;
    const int jspan  = M / JSPLIT;     // 512
    const int jbase  = blockIdx.y * jspan;
    const int NS     = (jspan / 64) * 4;   // 32 stages (8 j-tiles x 4 k-steps)

    // ---- aux staging (shared; the ONLY cross-wave LDS data) ----
    if (w < 2) {
        gload16(L + AUX_TCOL + w * 1024, (const char*)(tcol + jbase) + tid * 16);
        gload16(L + AUX_COEF + w * 1024, (const char*)(coef + jbase) + tid * 16);
    }
    if (w == 2 && l < 32)
        gload16(L + AUX_SROW, (const char*)(srow + row0) + l * 16);

    // ---- A strip into registers (held whole kernel) ----
    const char* Ab = (const char*)Abf;
    bf16x8 areg[4][8];
    #pragma unroll
    for (int mi = 0; mi < 4; ++mi) {
        int row = row0 + wr * 64 + mi * 16 + lo;
        #pragma unroll
        for (int kg = 0; kg < 8; ++kg)
            areg[mi][kg] = *(const bf16x8*)(Ab + (size_t)row * 512 + kg * 64 + hi * 16);
    }

    asm volatile("s_waitcnt vmcnt(0)" ::: "memory");   // drain ALL pre-loop VMEM
    __builtin_amdgcn_s_barrier();                      // aux visible; last barrier

    // per-lane row constants from LDS aux
    float sreg[4][4];
    #pragma unroll
    for (int mi = 0; mi < 4; ++mi)
        #pragma unroll
        for (int r = 0; r < 4; ++r)
            sreg[mi][r] = *(const float*)(L + AUX_SROW
                            + (wr * 64 + mi * 16 + hi * 4 + r) * 4);

    // ---- wave-private B ring: stage = 32 cols x 64 K = 4 KB, 4 gload16 ----
    const char* Bw = (const char*)Bbf + (size_t)jbase * 512;
    const int   cb0 = wc * 32;         // this wave's col offset inside a tile
    const int   ring0 = w * 12288;     // this wave's 3-slot ring base
    auto issueB = [&](int jt2, int kt2, int slot) {
        #pragma unroll
        for (int c = 0; c < 4; ++c) {
            int x   = c * 1024 + l * 16;             // linear offset in 4KB slot
            int col = x >> 7;                        // local col 0..31
            int src = (jt2 * 64 + cb0 + col) * 512 + kt2 * 128
                    + ((x & 127) ^ ((col & 7) << 4));
            gload16(L + ring0 + slot * 4096 + c * 1024, Bw + src);
        }
    };
    issueB(0, 0, 0);
    issueB(0, 1, 1);   // 8 outstanding (2 stages deep)

    float partial[4][4];
    #pragma unroll
    for (int mi = 0; mi < 4; ++mi)
        #pragma unroll
        for (int r = 0; r < 4; ++r) partial[mi][r] = 0.0f;

    const float K2G = 2.0f * GAMMA_ * LOG2E_;

    f32x4 acc[4][2];

    for (int s = 0; s < NS; ++s) {
        const int jt   = s >> 2;
        const int kt   = s & 3;
        const int slot = s % 3;

        if (kt == 0) {
            #pragma unroll
            for (int mi = 0; mi < 4; ++mi)
                #pragma unroll
                for (int ni = 0; ni < 2; ++ni) {
                    f32x4 z = {0.f, 0.f, 0.f, 0.f};
                    acc[mi][ni] = z;
                }
        }

        // ---- issue stage s+2 into slot (s+2)%3; counted wait for stage s ----
        if (s + 2 < NS) {
            const int s2 = s + 2;
            issueB(s2 >> 2, s2 & 3, s2 % 3);
            asm volatile("s_waitcnt vmcnt(8)" ::: "memory");
        } else if (s == NS - 2) {
            asm volatile("s_waitcnt vmcnt(4)" ::: "memory");
        } else {
            asm volatile("s_waitcnt vmcnt(0)" ::: "memory");
        }

        // ---- ds_read own slot (swizzled), 16 MFMA ----
        bf16x8 bb[2][2];
        #pragma unroll
        for (int ni = 0; ni < 2; ++ni) {
            int col = ni * 16 + lo;
            #pragma unroll
            for (int ks = 0; ks < 2; ++ks) {
                int off = ring0 + slot * 4096 + col * 128
                        + ((ks * 64 + hi * 16) ^ ((col & 7) << 4));
                bb[ni][ks] = *(const bf16x8*)(L + off);
            }
        }
        __builtin_amdgcn_s_setprio(1);
        #pragma unroll
        for (int ks = 0; ks < 2; ++ks)
            #pragma unroll
            for (int mi = 0; mi < 4; ++mi)
                #pragma unroll
                for (int ni = 0; ni < 2; ++ni)
                    acc[mi][ni] = __builtin_amdgcn_mfma_f32_16x16x32_bf16(
                        areg[mi][kt * 2 + ks], bb[ni][ks], acc[mi][ni], 0, 0, 0);
        __builtin_amdgcn_s_setprio(0);

        // ---- per-j-tile fused epilogue: exp2 + weighted row-accumulate ----
        if (kt == 3) {
            #pragma unroll
            for (int ni = 0; ni < 2; ++ni) {
                int cl = jt * 64 + cb0 + ni * 16 + lo;
                float t  = *(const float*)(L + AUX_TCOL + cl * 4);
                float cf = *(const float*)(L + AUX_COEF + cl * 4);
                #pragma unroll
                for (int mi = 0; mi < 4; ++mi) {
                    #pragma unroll
                    for (int r = 0; r < 4; ++r) {
                        float arg = fmaf(acc[mi][ni][r], K2G, sreg[mi][r] + t);
                        float p = __builtin_amdgcn_exp2f(arg);
                        partial[mi][r] = fmaf(p, cf, partial[mi][r]);
                    }
                }
            }
        }
    }

    // ---- reduce across the 16 lanes of each row group, one atomic per row ----
    #pragma unroll
    for (int mi = 0; mi < 4; ++mi) {
        #pragma unroll
        for (int r = 0; r < 4; ++r) {
            float v = partial[mi][r];
            v += __shfl_xor(v, 1);
            v += __shfl_xor(v, 2);
            v += __shfl_xor(v, 4);
            v += __shfl_xor(v, 8);
            if (lo == 0) {
                int rowg = row0 + wr * 64 + mi * 16 + hi * 4 + r;
                atomicAdd(&out[rowg], v);
            }
        }
    }
}

// ---------- launcher ----------
extern "C" void kernel_launch(void* const* d_in, const int* in_sizes, int n_in,
                              void* d_out, int out_size, void* d_ws, size_t ws_size,
                              hipStream_t stream) {
    const float* X      = (const float*)d_in[0];
    const float* Xt     = (const float*)d_in[1];
    const float* alphas = (const float*)d_in[2];
    const float* y      = (const float*)d_in[3];
    const float* b      = (const float*)d_in[4];
    float* out = (float*)d_out;

    const int N = in_sizes[0] / D;   // 8192
    const int M = in_sizes[1] / D;   // 8192

    // workspace: bf16 X | bf16 Xt | srow[N] | tcol[M] | coef[M]
    char* ws = (char*)d_ws;
    unsigned short* Abf = (unsigned short*)ws;
    unsigned short* Bbf = Abf + (size_t)N * D;
    float* srow = (float*)(Bbf + (size_t)M * D);
    float* tcol = srow + N;
    float* coef = tcol + M;

    prep_all_kernel<<<(N + M) / 4, 256, 0, stream>>>(X, Xt, alphas, y, b,
                                                     Abf, Bbf, srow, tcol, coef,
                                                     out, N, M);

    dim3 grid(N / BM, JSPLIT);   // 64 x 16 = 1024 blocks
    svm_main_kernel<<<grid, 256, 0, stream>>>(Abf, Bbf, srow, tcol, coef, out, M);
}

// Round 11
// 52.497 us; speedup vs baseline: 3.8890x; 3.8890x over previous
//
#include <hip/hip_runtime.h>

typedef __attribute__((ext_vector_type(8))) short bf16x8;
typedef __attribute__((ext_vector_type(4))) float f32x4;

#define GAMMA_ 0.5f
#define LOG2E_ 1.4426950408889634f

constexpr int D      = 256;   // feature dim (K)
constexpr int BM     = 128;   // rows of X per block (2 row-groups of 64)
constexpr int JSPLIT = 8;     // split of M across blockIdx.y

// LDS layout (bytes):
//   [0, 65536)      : per-wave B rings, wave w at [w*16384, +16K): 4 slots x 4KB
//   [65536, 69632)  : tcol panel (1024 x f32)
//   [69632, 73728)  : coef panel (1024 x f32)
//   [73728, 74240)  : srow panel (128 x f32)
constexpr int AUX_TCOL  = 65536;
constexpr int AUX_COEF  = 69632;
constexpr int AUX_SROW  = 73728;
constexpr int LDS_BYTES = 74240;

// ---------- helpers ----------
__device__ __forceinline__ unsigned short f2bf(float f) {
    unsigned int x = __float_as_uint(f);
    x += 0x7FFFu + ((x >> 16) & 1u);          // RNE
    return (unsigned short)(x >> 16);
}

__device__ __forceinline__ void gload16(void* lds, const void* g) {
    __builtin_amdgcn_global_load_lds(
        (const __attribute__((address_space(1))) void*)g,
        (__attribute__((address_space(3))) void*)lds, 16, 0, 0);
}

// ---------- prep: cast to bf16, row |x|^2, coefs, out-init ----------
__global__ void prep_all_kernel(const float* __restrict__ X,
                                const float* __restrict__ Xt,
                                const float* __restrict__ alphas,
                                const float* __restrict__ y,
                                const float* __restrict__ b,
                                unsigned short* __restrict__ Abf,
                                unsigned short* __restrict__ Bbf,
                                float* __restrict__ srow,
                                float* __restrict__ tcol,
                                float* __restrict__ coef,
                                float* __restrict__ out,
                                int N, int M) {
    int w = threadIdx.x >> 6;         // one wave per row
    int l = threadIdx.x & 63;
    int row = blockIdx.x * 4 + w;
    if (row >= N + M) return;
    const float* src;
    unsigned short* dst;
    if (row < N) { src = X  + (size_t)row * D;       dst = Abf + (size_t)row * D; }
    else         { src = Xt + (size_t)(row - N) * D; dst = Bbf + (size_t)(row - N) * D; }
    const float4 v = reinterpret_cast<const float4*>(src)[l];
    ushort4 u;
    u.x = f2bf(v.x); u.y = f2bf(v.y); u.z = f2bf(v.z); u.w = f2bf(v.w);
    reinterpret_cast<ushort4*>(dst)[l] = u;
    float ss = v.x * v.x + v.y * v.y + v.z * v.z + v.w * v.w;
    #pragma unroll
    for (int off = 32; off >= 1; off >>= 1) ss += __shfl_xor(ss, off);
    if (l == 0) {
        float folded = -GAMMA_ * LOG2E_ * ss;
        if (row < N) { srow[row] = folded; out[row] = b[0]; }
        else {
            int r2 = row - N;
            tcol[r2] = folded;
            coef[r2] = alphas[r2] * y[r2];
        }
    }
}

// ---------- fused RBF-SVM predict ----------
// pred_i = sum_j exp2( s_i + t_j + (2*g*log2e) * <x_i, xt_j> ) * coef_j + b
// Barrier-free wave-private pipeline + REGISTER-DOUBLE-BUFFERED B fragments:
// per stage: issue DMA s+3 -> vmcnt(8) (stage s+1 landed) -> ds_read slot(s+1)
// into other buffer -> 16 MFMA on current buffer (LDS latency hidden under
// MFMA; compiler emits counted lgkmcnt, not 0).
__launch_bounds__(256, 2)
__global__ void svm_main_kernel(const unsigned short* __restrict__ Abf,
                                const unsigned short* __restrict__ Bbf,
                                const float* __restrict__ srow,
                                const float* __restrict__ tcol,
                                const float* __restrict__ coef,
                                float* __restrict__ out,
                                int M) {
    __shared__ char L[LDS_BYTES];

    const int tid = threadIdx.x;
    const int w   = tid >> 6;          // wave 0..3
    const int l   = tid & 63;
    const int wr  = w >> 1;            // row group 0..1
    const int wc  = w & 1;             // col half 0..1 (wave-private cols)
    const int hi  = l >> 4;            // 0..3
    const int lo  = l & 15;
    const int row0   = blockIdx.x * BM;
    const int jspan  = M / JSPLIT;     // 1024
    const int jbase  = blockIdx.y * jspan;
    const int JT     = jspan / 64;     // 16 j-tiles; wave takes 32 cols of each

    // ---- aux staging (shared; the ONLY cross-wave LDS data) ----
    gload16(L + AUX_TCOL + w * 1024, (const char*)(tcol + jbase) + tid * 16);
    gload16(L + AUX_COEF + w * 1024, (const char*)(coef + jbase) + tid * 16);
    if (w == 0 && l < 32)
        gload16(L + AUX_SROW, (const char*)(srow + row0) + l * 16);

    // ---- A strip into registers (held whole kernel) ----
    const char* Ab = (const char*)Abf;
    bf16x8 areg[4][8];
    #pragma unroll
    for (int mi = 0; mi < 4; ++mi) {
        int row = row0 + wr * 64 + mi * 16 + lo;
        #pragma unroll
        for (int kg = 0; kg < 8; ++kg)
            areg[mi][kg] = *(const bf16x8*)(Ab + (size_t)row * 512 + kg * 64 + hi * 16);
    }

    asm volatile("s_waitcnt vmcnt(0)" ::: "memory");   // drain ALL pre-loop VMEM
    __builtin_amdgcn_s_barrier();                      // aux visible; last barrier

    // per-lane row constants from LDS aux
    float sreg[4][4];
    #pragma unroll
    for (int mi = 0; mi < 4; ++mi)
        #pragma unroll
        for (int r = 0; r < 4; ++r)
            sreg[mi][r] = *(const float*)(L + AUX_SROW
                            + (wr * 64 + mi * 16 + hi * 4 + r) * 4);

    // ---- wave-private B ring: stage = 32 cols x 64 K = 4 KB, 4 gload16 ----
    const char* Bw = (const char*)Bbf + (size_t)jbase * 512;
    const int   cb0 = wc * 32;         // this wave's col offset inside a tile
    const int   ring0 = w * 16384;     // this wave's 4-slot ring base
    auto issueB = [&](int jt2, int kt2, int slot) {
        #pragma unroll
        for (int c = 0; c < 4; ++c) {
            int x   = c * 1024 + l * 16;             // linear offset in 4KB slot
            int col = x >> 7;                        // local col 0..31
            int src = (jt2 * 64 + cb0 + col) * 512 + kt2 * 128
                    + ((x & 127) ^ ((col & 7) << 4));
            gload16(L + ring0 + slot * 4096 + c * 1024, Bw + src);
        }
    };

    float partial[4][4];
    #pragma unroll
    for (int mi = 0; mi < 4; ++mi)
        #pragma unroll
        for (int r = 0; r < 4; ++r) partial[mi][r] = 0.0f;

    const float K2G = 2.0f * GAMMA_ * LOG2E_;

    f32x4 acc[4][2];
    bf16x8 bufE[2][2], bufO[2][2];     // named register double-buffer (rule #20)

#define DSREAD(BUF, SLOT)                                                      \
    {                                                                          \
        _Pragma("unroll")                                                      \
        for (int ni = 0; ni < 2; ++ni) {                                       \
            int col = ni * 16 + lo;                                            \
            _Pragma("unroll")                                                  \
            for (int ks = 0; ks < 2; ++ks) {                                   \
                int off = ring0 + (SLOT) * 4096 + col * 128                    \
                        + ((ks * 64 + hi * 16) ^ ((col & 7) << 4));            \
                BUF[ni][ks] = *(const bf16x8*)(L + off);                       \
            }                                                                  \
        }                                                                      \
    }

#define MMA(BUF, KT)                                                           \
    {                                                                          \
        __builtin_amdgcn_s_setprio(1);                                         \
        _Pragma("unroll")                                                      \
        for (int ks = 0; ks < 2; ++ks)                                         \
            _Pragma("unroll")                                                  \
            for (int mi = 0; mi < 4; ++mi)                                     \
                _Pragma("unroll")                                              \
                for (int ni = 0; ni < 2; ++ni)                                 \
                    acc[mi][ni] = __builtin_amdgcn_mfma_f32_16x16x32_bf16(     \
                        areg[mi][(KT) * 2 + ks], BUF[ni][ks],                  \
                        acc[mi][ni], 0, 0, 0);                                 \
        __builtin_amdgcn_s_setprio(0);                                         \
    }

#define ACC_INIT                                                               \
    {                                                                          \
        _Pragma("unroll")                                                      \
        for (int mi = 0; mi < 4; ++mi)                                         \
            _Pragma("unroll")                                                  \
            for (int ni = 0; ni < 2; ++ni) {                                   \
                f32x4 z = {0.f, 0.f, 0.f, 0.f};                                \
                acc[mi][ni] = z;                                               \
            }                                                                  \
    }

#define EPILOGUE(JT_)                                                          \
    {                                                                          \
        _Pragma("unroll")                                                      \
        for (int ni = 0; ni < 2; ++ni) {                                       \
            int cl = (JT_) * 64 + cb0 + ni * 16 + lo;                          \
            float t  = *(const float*)(L + AUX_TCOL + cl * 4);                 \
            float cf = *(const float*)(L + AUX_COEF + cl * 4);                 \
            _Pragma("unroll")                                                  \
            for (int mi = 0; mi < 4; ++mi) {                                   \
                _Pragma("unroll")                                              \
                for (int r = 0; r < 4; ++r) {                                  \
                    float arg = fmaf(acc[mi][ni][r], K2G, sreg[mi][r] + t);    \
                    float p = __builtin_amdgcn_exp2f(arg);                     \
                    partial[mi][r] = fmaf(p, cf, partial[mi][r]);              \
                }                                                              \
            }                                                                  \
        }                                                                      \
    }

    // ---- prologue: stages (0,0..2) in flight; first fragments in bufE ----
    issueB(0, 0, 0);
    issueB(0, 1, 1);
    issueB(0, 2, 2);                                   // 12 outstanding
    asm volatile("s_waitcnt vmcnt(8)" ::: "memory");   // stage (0,0) landed
    DSREAD(bufE, 0);

    for (int jt = 0; jt < JT; ++jt) {
        ACC_INIT;
        const bool more = (jt + 1 < JT);
        // kt = 0 : compute bufE(slot kt0), prefetch slot1 -> bufO
        issueB(jt, 3, 3);
        asm volatile("s_waitcnt vmcnt(8)" ::: "memory");    // (jt,1) landed
        DSREAD(bufO, 1);
        MMA(bufE, 0);
        // kt = 1 : compute bufO(slot1), prefetch slot2 -> bufE
        if (more) {
            issueB(jt + 1, 0, 0);
            asm volatile("s_waitcnt vmcnt(8)" ::: "memory");  // (jt,2) landed
        } else {
            asm volatile("s_waitcnt vmcnt(4)" ::: "memory");
        }
        DSREAD(bufE, 2);
        MMA(bufO, 1);
        // kt = 2 : compute bufE(slot2), prefetch slot3 -> bufO
        if (more) {
            issueB(jt + 1, 1, 1);
            asm volatile("s_waitcnt vmcnt(8)" ::: "memory");  // (jt,3) landed
        } else {
            asm volatile("s_waitcnt vmcnt(0)" ::: "memory");
        }
        DSREAD(bufO, 3);
        MMA(bufE, 2);
        // kt = 3 : compute bufO(slot3), prefetch next jt's slot0 -> bufE
        if (more) {
            issueB(jt + 1, 2, 2);
            asm volatile("s_waitcnt vmcnt(8)" ::: "memory");  // (jt+1,0) landed
            DSREAD(bufE, 0);
        }
        MMA(bufO, 3);
        EPILOGUE(jt);
    }
#undef DSREAD
#undef MMA
#undef ACC_INIT
#undef EPILOGUE

    // ---- reduce across the 16 lanes of each row group, one atomic per row ----
    #pragma unroll
    for (int mi = 0; mi < 4; ++mi) {
        #pragma unroll
        for (int r = 0; r < 4; ++r) {
            float v = partial[mi][r];
            v += __shfl_xor(v, 1);
            v += __shfl_xor(v, 2);
            v += __shfl_xor(v, 4);
            v += __shfl_xor(v, 8);
            if (lo == 0) {
                int rowg = row0 + wr * 64 + mi * 16 + hi * 4 + r;
                atomicAdd(&out[rowg], v);
            }
        }
    }
}

// ---------- launcher ----------
extern "C" void kernel_launch(void* const* d_in, const int* in_sizes, int n_in,
                              void* d_out, int out_size, void* d_ws, size_t ws_size,
                              hipStream_t stream) {
    const float* X      = (const float*)d_in[0];
    const float* Xt     = (const float*)d_in[1];
    const float* alphas = (const float*)d_in[2];
    const float* y      = (const float*)d_in[3];
    const float* b      = (const float*)d_in[4];
    float* out = (float*)d_out;

    const int N = in_sizes[0] / D;   // 8192
    const int M = in_sizes[1] / D;   // 8192

    // workspace: bf16 X | bf16 Xt | srow[N] | tcol[M] | coef[M]
    char* ws = (char*)d_ws;
    unsigned short* Abf = (unsigned short*)ws;
    unsigned short* Bbf = Abf + (size_t)N * D;
    float* srow = (float*)(Bbf + (size_t)M * D);
    float* tcol = srow + N;
    float* coef = tcol + M;

    prep_all_kernel<<<(N + M) / 4, 256, 0, stream>>>(X, Xt, alphas, y, b,
                                                     Abf, Bbf, srow, tcol, coef,
                                                     out, N, M);

    dim3 grid(N / BM, JSPLIT);   // 64 x 8 = 512 blocks = 2 per CU
    svm_main_kernel<<<grid, 256, 0, stream>>>(Abf, Bbf, srow, tcol, coef, out, M);
}